// Round 7
// baseline (336.103 us; speedup 1.0000x reference)
//
#include <hip/hip_runtime.h>
#include <math.h>

// Problem constants
#define B_DIM 8
#define T_DIM 4096
#define K_DIM 1024   // IN_DIM
#define H_DIM 1024   // HIDDEN
#define M_DIM (B_DIM * T_DIM)   // 32768 rows

#define CH 64               // scan chunk length
#define NC (T_DIM / CH)     // 64 chunks per channel
#define BK 64               // GEMM K-step
#define NKS (K_DIM / BK)    // 16 K-steps

typedef short bf16x8 __attribute__((ext_vector_type(8)));   // 8 bf16 = 4 VGPRs
typedef float f32x4  __attribute__((ext_vector_type(4)));

// ---------- helpers ----------
__device__ __forceinline__ unsigned short f2bf(float f) {
  unsigned int u = __builtin_bit_cast(unsigned int, f);
  u += 0x7FFFu + ((u >> 16) & 1u);   // round-to-nearest-even
  return (unsigned short)(u >> 16);
}

__device__ __forceinline__ void gload_lds16(const void* g, void* l) {
  __builtin_amdgcn_global_load_lds(
      (const __attribute__((address_space(1))) unsigned int*)g,
      (__attribute__((address_space(3))) unsigned int*)l,
      16 /*bytes, literal*/, 0 /*offset*/, 0 /*aux*/);
}

// fast softplus: v_exp_f32 + v_log_f32
__device__ __forceinline__ float softplus_fast(float x) {
  float e = __expf(-fabsf(x));
  return fmaxf(x, 0.f) + __logf(1.f + e);
}

// fast tanh: 1 - 2/(e^{2x}+1). e=inf -> 1, e=0 -> -1 (correct saturation).
__device__ __forceinline__ float tanh_fast(float x) {
  float e = __expf(2.f * x);
  return 1.f - 2.f * __builtin_amdgcn_rcpf(e + 1.f);
}

// ---------- f32 -> bf16 convert (8 elems/thread) ----------
__global__ __launch_bounds__(256) void k_cvt(const float* __restrict__ in,
                                             unsigned short* __restrict__ out,
                                             int n8) {
  int i = blockIdx.x * 256 + threadIdx.x;
  if (i >= n8) return;
  float4 v0 = ((const float4*)in)[i * 2 + 0];
  float4 v1 = ((const float4*)in)[i * 2 + 1];
  bf16x8 r;
  r[0] = (short)f2bf(v0.x); r[1] = (short)f2bf(v0.y);
  r[2] = (short)f2bf(v0.z); r[3] = (short)f2bf(v0.w);
  r[4] = (short)f2bf(v1.x); r[5] = (short)f2bf(v1.y);
  r[6] = (short)f2bf(v1.z); r[7] = (short)f2bf(v1.w);
  ((bf16x8*)out)[i] = r;
}

// 16-MFMA quadrant cluster; all acc indices compile-time (rule 20).
#define MFMA_Q(AF, BF, MQ, NQ)                                                 \
  do {                                                                         \
    __builtin_amdgcn_s_setprio(1);                                             \
    _Pragma("unroll")                                                          \
    for (int mm = 0; mm < 4; mm++)                                             \
      _Pragma("unroll")                                                        \
      for (int nn = 0; nn < 2; nn++)                                           \
        _Pragma("unroll")                                                      \
        for (int kk = 0; kk < 2; kk++)                                         \
          acc[(MQ)*4 + mm][(NQ)*2 + nn] =                                      \
              __builtin_amdgcn_mfma_f32_16x16x32_bf16(                         \
                  AF[mm*2 + kk], BF[nn*2 + kk],                                \
                  acc[(MQ)*4 + mm][(NQ)*2 + nn], 0, 0, 0);                     \
    __builtin_amdgcn_s_setprio(0);                                             \
  } while (0)

// ---------- dual GEMM: zero-VALU K-loop addressing ----------
// BM=256 rows of X, 128 h-cols per block; virtual B = 256 rows interleaving
// Wd/Wb at 32-col granularity. 8 waves (2Mx4N), wave = 128 rows x 64 vcols.
// Addressing: swizzle chunk ch=(kk*4+hi)^(fr&7) is fragment-independent
// (all row offsets are multiples of 8), so 4 per-thread LDS base pointers +
// compile-time immediate offsets cover all 24 ds_read_b128 per tile; the
// 2-tile unrolled loop makes the buffer offset (d*32768) an immediate too.
// One vmcnt(0)+barrier per tile; staging issued first in body (ages ~1 tile).
__global__ __launch_bounds__(512, 2) void k_gemm_dual(
    const unsigned short* __restrict__ Xb,    // [M][K] bf16 bits
    const unsigned short* __restrict__ Wdb,   // [H][K] bf16 bits
    const unsigned short* __restrict__ Wbb,   // [H][K] bf16 bits
    const float* __restrict__ bd,
    const float* __restrict__ bb,
    const float* __restrict__ A_log,
    float* __restrict__ a_out,                // [M][H]
    float* __restrict__ b_out,                // [M][H] (aliases d_out)
    float* __restrict__ aggA,                 // [B*NC][H]
    float* __restrict__ aggB)                 // [B*NC][H]
{
  __shared__ unsigned short As[2][256 * BK];   // 2 x 32 KiB
  __shared__ unsigned short Bs[2][256 * BK];   // 2 x 32 KiB  -> 128 KiB

  const int tid  = threadIdx.x;
  // XCD-grouped mapping: 1024 blocks = 8 XCD x 128; n-tile fastest.
  const int wgid = blockIdx.x;
  const int xcd  = wgid & 7;
  const int j    = wgid >> 3;                 // 0..127 per XCD
  const int bm   = (xcd * 16 + (j >> 3)) * 256;   // m-tile (256 rows)
  const int bn   = (j & 7) * 128;                 // h-col base (128 cols)

  const int w    = tid >> 6;
  const int lane = tid & 63;
  const int wm   = (w >> 2) * 128;   // 2 wave-rows of 128
  const int wq   = w & 3;            // 4 wave-col-quarters
  const int wn   = wq * 64;          // virtual col base

  f32x4 acc[8][4];
  const f32x4 z4 = {0.f, 0.f, 0.f, 0.f};
#pragma unroll
  for (int m = 0; m < 8; m++)
#pragma unroll
    for (int n = 0; n < 4; n++) acc[m][n] = z4;

  const int fr = lane & 15;
  const int hi = lane >> 4;

  // ---- staging invariants (computed once) ----
  // idx = jj*512+tid; row = idx>>3; pre-swizzled global chunk cg = c^(row&7).
  const unsigned short* gA[4];
  const unsigned short* gB[4];
  int ldsoff[4];
#pragma unroll
  for (int jj = 0; jj < 4; jj++) {
    int idx = jj * 512 + tid;        // 0..2047
    int row = idx >> 3;              // 0..255
    int cg  = (idx & 7) ^ (row & 7);
    ldsoff[jj] = idx * 16;
    gA[jj] = Xb + (size_t)(bm + row) * K_DIM + (size_t)(cg * 8);
    int h = bn + (row >> 6) * 32 + (row & 31);       // virtual row -> h col
    const unsigned short* Wsrc = (row & 32) ? Wbb : Wdb;
    gB[jj] = Wsrc + (size_t)h * K_DIM + (size_t)(cg * 8);
  }

#define STAGE(T, D)                                                           \
  do {                                                                        \
    _Pragma("unroll")                                                         \
    for (int jj = 0; jj < 4; jj++) {                                          \
      gload_lds16(gA[jj] + (T) * BK, (char*)As[D] + ldsoff[jj]);              \
      gload_lds16(gB[jj] + (T) * BK, (char*)Bs[D] + ldsoff[jj]);              \
    }                                                                         \
  } while (0)

  // ---- ds_read base pointers (all K-loop addressing folds to immediates) --
  const int ch0 = hi ^ (fr & 7);          // kk=0 swizzled chunk
  const int ch1 = ch0 ^ 4;                // kk=1
  const char* bA0 = (const char*)As + (size_t)((wm + fr) * 128 + ch0 * 16);
  const char* bA1 = (const char*)As + (size_t)((wm + fr) * 128 + ch1 * 16);
  const char* bB0 = (const char*)Bs + (size_t)((wn + fr) * 128 + ch0 * 16);
  const char* bB1 = (const char*)Bs + (size_t)((wn + fr) * 128 + ch1 * 16);

#define RDA(DST, D, MQ)                                                       \
  _Pragma("unroll")                                                           \
  for (int mm = 0; mm < 4; mm++) {                                            \
    DST[mm*2+0] = *(const bf16x8*)(bA0 + (D)*32768 + ((MQ)*64 + mm*16)*128);  \
    DST[mm*2+1] = *(const bf16x8*)(bA1 + (D)*32768 + ((MQ)*64 + mm*16)*128);  \
  }
#define RDB(DST, D, NQ)                                                       \
  _Pragma("unroll")                                                           \
  for (int nn = 0; nn < 2; nn++) {                                            \
    DST[nn*2+0] = *(const bf16x8*)(bB0 + (D)*32768 + ((NQ)*32 + nn*16)*128);  \
    DST[nn*2+1] = *(const bf16x8*)(bB1 + (D)*32768 + ((NQ)*32 + nn*16)*128);  \
  }

  // tile body: stage(t+1) first (ages a full tile), quadrants ordered so A0
  // dies before A1 loads (peak live ~192 regs + acc). One barrier per tile.
#define TILE(T, D, NXT)                                                       \
  do {                                                                        \
    if (NXT) STAGE((T) + 1, (D) ^ 1);                                         \
    bf16x8 A0[8], A1[8], B0[4], B1[4];                                        \
    RDA(A0, D, 0); RDB(B0, D, 0);                                             \
    MFMA_Q(A0, B0, 0, 0);                                                     \
    RDB(B1, D, 1);                                                            \
    MFMA_Q(A0, B1, 0, 1);                                                     \
    RDA(A1, D, 1);                                                            \
    MFMA_Q(A1, B0, 1, 0);                                                     \
    MFMA_Q(A1, B1, 1, 1);                                                     \
    if (NXT) {                                                                \
      asm volatile("s_waitcnt vmcnt(0)" ::: "memory");                        \
      __builtin_amdgcn_s_barrier();                                           \
    }                                                                         \
  } while (0)

  // prologue: fill buffer 0
  STAGE(0, 0);
  asm volatile("s_waitcnt vmcnt(0)" ::: "memory");
  __builtin_amdgcn_s_barrier();

#pragma unroll 1
  for (int t = 0; t < NKS; t += 2) {
    TILE(t,     0, true);
    TILE(t + 1, 1, (t + 2) < NKS);
  }

  // epilogue: C/D layout col = lane&15, row = (lane>>4)*4 + r  [m89-verified]
  // acc[m][np] = z1, acc[m][np+2] = z2, same h-col gn. Wave rows = 2 chunks.
  const int col   = fr;
  const int rbase = hi * 4;
  const int bidx  = bm >> 12;                            // batch (T=4096)
  const int cch0  = ((bm + wm) & (T_DIM - 1)) >> 6;      // first chunk id

#pragma unroll
  for (int np = 0; np < 2; np++) {
    int gn = bn + wq * 32 + np * 16 + col;
    float bdv = bd[gn];
    float bbv = bb[gn];
    float Ah  = __expf(A_log[gn]);
    float segA[8], segB[8];
#pragma unroll
    for (int m = 0; m < 8; m++) {
      float sA = 1.f, sB = 0.f;
#pragma unroll
      for (int r = 0; r < 4; r++) {
        int gm = bm + wm + m * 16 + rbase + r;
        float z1  = acc[m][np][r] + bdv;
        float z2  = acc[m][np + 2][r] + bbv;
        float dlt = softplus_fast(z1);
        float av  = __expf(-dlt * Ah);
        float bv  = dlt * z2;
        size_t off = (size_t)gm * H_DIM + (size_t)gn;
        a_out[off] = av;
        b_out[off] = bv;
        sB = fmaf(av, sB, bv);     // compose ascending t within 4-row run
        sA *= av;
      }
      segA[m] = sA; segB[m] = sB;
    }
    // ordered cross-lane compose per 64-row chunk group (m 0..3 / 4..7)
#pragma unroll
    for (int g = 0; g < 2; g++) {
      float chA = 1.f, chB = 0.f;
#pragma unroll
      for (int mi = 0; mi < 4; mi++) {
        int m = g * 4 + mi;
#pragma unroll
        for (int h2 = 0; h2 < 4; h2++) {
          float sa = __shfl(segA[m], col + h2 * 16, 64);
          float sb = __shfl(segB[m], col + h2 * 16, 64);
          chB = fmaf(sa, chB, sb);
          chA *= sa;
        }
      }
      if (lane < 16) {
        size_t o = ((size_t)(bidx * NC + cch0 + g) << 10) + (size_t)gn;
        aggA[o] = chA;
        aggB[o] = chB;
      }
    }
  }
}

// ---------- scan pass 2: sequential scan over chunk aggregates ----------
__global__ __launch_bounds__(256) void k_scan_chunks(
    const float* __restrict__ aggA, const float* __restrict__ aggB,
    const float* __restrict__ h0, float* __restrict__ hstart)
{
  int idx = blockIdx.x * 256 + threadIdx.x;   // b*H + h
  int h   = idx & (H_DIM - 1);
  int b   = idx >> 10;
  float hc = h0[idx];
  for (int c = 0; c < NC; c++) {
    size_t o = ((size_t)(b * NC + c) << 10) + (size_t)h;
    hstart[o] = hc;
    hc = fmaf(aggA[o], hc, aggB[o]);
  }
}

// ---------- scan pass 3: re-apply within chunk + tanh ----------
__global__ __launch_bounds__(256) void k_scan_apply(
    const float* __restrict__ a_arr, const float* b_arr,
    const float* __restrict__ hstart, float* out)   // b_arr aliases out!
{
  int idx = blockIdx.x * 256 + threadIdx.x;
  int h   = idx & (H_DIM - 1);
  int bc  = idx >> 10;
  int c   = bc & (NC - 1);
  int b   = bc >> 6;
  size_t base = ((size_t)b * T_DIM + (size_t)c * CH) * H_DIM + (size_t)h;
  float hc = hstart[idx];
#pragma unroll 4
  for (int i = 0; i < CH; i++) {
    size_t o = base + (size_t)i * H_DIM;
    float at = a_arr[o];
    float bt = b_arr[o];       // read BEFORE the aliased write below
    hc = fmaf(at, hc, bt);
    out[o] = tanh_fast(hc);
  }
}

// ---------- launch ----------
extern "C" void kernel_launch(void* const* d_in, const int* in_sizes, int n_in,
                              void* d_out, int out_size, void* d_ws, size_t ws_size,
                              hipStream_t stream) {
  const float* x     = (const float*)d_in[0];
  const float* h0    = (const float*)d_in[1];
  const float* Wd    = (const float*)d_in[2];
  const float* bd    = (const float*)d_in[3];
  const float* Wb    = (const float*)d_in[4];
  const float* bb    = (const float*)d_in[5];
  const float* A_log = (const float*)d_in[6];
  float* out = (float*)d_out;

  char* ws = (char*)d_ws;
  unsigned short* xb   = (unsigned short*)(ws + 0);           //  64 MiB
  unsigned short* wdb  = (unsigned short*)(ws + 67108864);    //   2 MiB
  unsigned short* wbb  = (unsigned short*)(ws + 69206016);    //   2 MiB
  float*          aarr = (float*)(ws + 71303168);             // 128 MiB
  float*          aggA = (float*)(ws + 205520896);            //   2 MiB
  float*          aggB = (float*)(ws + 207618048);            //   2 MiB
  float*          hst  = (float*)(ws + 209715200);            //   2 MiB
  float*          barr = out;  // b_t staged in d_out, overwritten by k_scan_apply

  // converts
  k_cvt<<<(M_DIM * K_DIM / 8) / 256, 256, 0, stream>>>(x, xb, M_DIM * K_DIM / 8);
  k_cvt<<<(H_DIM * K_DIM / 8) / 256, 256, 0, stream>>>(Wd, wdb, H_DIM * K_DIM / 8);
  k_cvt<<<(H_DIM * K_DIM / 8) / 256, 256, 0, stream>>>(Wb, wbb, H_DIM * K_DIM / 8);

  // fused dual GEMM + nonlinearity + chunk-aggregate epilogue
  k_gemm_dual<<<(M_DIM / 256) * (H_DIM / 128), 512, 0, stream>>>(
      xb, wdb, wbb, bd, bb, A_log, aarr, barr, aggA, aggB);

  // chunked affine scan over T (agg pass fused into GEMM)
  k_scan_chunks<<<(B_DIM * H_DIM) / 256,      256, 0, stream>>>(aggA, aggB, h0, hst);
  k_scan_apply <<<(B_DIM * NC * H_DIM) / 256, 256, 0, stream>>>(aarr, barr, hst, out);
}

// Round 8
// 316.449 us; speedup vs baseline: 1.0621x; 1.0621x over previous
//
#include <hip/hip_runtime.h>
#include <math.h>

// Problem constants
#define B_DIM 8
#define T_DIM 4096
#define K_DIM 1024   // IN_DIM
#define H_DIM 1024   // HIDDEN
#define M_DIM (B_DIM * T_DIM)   // 32768 rows
#define BK 64
#define NTT 256             // 16 m-tiles x 16 k-tiles per block

typedef short bf16x8 __attribute__((ext_vector_type(8)));   // 8 bf16 = 4 VGPRs
typedef float f32x4  __attribute__((ext_vector_type(4)));

// ---------- helpers ----------
__device__ __forceinline__ unsigned short f2bf(float f) {
  unsigned int u = __builtin_bit_cast(unsigned int, f);
  u += 0x7FFFu + ((u >> 16) & 1u);   // round-to-nearest-even
  return (unsigned short)(u >> 16);
}

__device__ __forceinline__ void gload_lds16(const void* g, void* l) {
  __builtin_amdgcn_global_load_lds(
      (const __attribute__((address_space(1))) unsigned int*)g,
      (__attribute__((address_space(3))) unsigned int*)l,
      16 /*bytes, literal*/, 0 /*offset*/, 0 /*aux*/);
}

__device__ __forceinline__ float softplus_fast(float x) {
  float e = __expf(-fabsf(x));
  return fmaxf(x, 0.f) + __logf(1.f + e);
}

// fast tanh: 1 - 2/(e^{2x}+1). e=inf -> 1, e=0 -> -1 (correct saturation).
__device__ __forceinline__ float tanh_fast(float x) {
  float e = __expf(2.f * x);
  return 1.f - 2.f * __builtin_amdgcn_rcpf(e + 1.f);
}

// ---------- f32 -> bf16 convert (8 elems/thread) ----------
__global__ __launch_bounds__(256) void k_cvt(const float* __restrict__ in,
                                             unsigned short* __restrict__ out,
                                             int n8) {
  int i = blockIdx.x * 256 + threadIdx.x;
  if (i >= n8) return;
  float4 v0 = ((const float4*)in)[i * 2 + 0];
  float4 v1 = ((const float4*)in)[i * 2 + 1];
  bf16x8 r;
  r[0] = (short)f2bf(v0.x); r[1] = (short)f2bf(v0.y);
  r[2] = (short)f2bf(v0.z); r[3] = (short)f2bf(v0.w);
  r[4] = (short)f2bf(v1.x); r[5] = (short)f2bf(v1.y);
  r[6] = (short)f2bf(v1.z); r[7] = (short)f2bf(v1.w);
  ((bf16x8*)out)[i] = r;
}

// ---------- megakernel: dual GEMM + online chunked scan + tanh ----------
// Grid = 8 batches x 32 col-tiles = 256 blocks (1/CU, single round). Each
// block owns a full (batch, 32-col) T-chain: loops 16 m-tiles of 256 rows.
// Per m-tile: dual GEMM (virtual B interleaves Wd/Wb at 16-col granularity:
// vrow [0:16)=Wd[0:16), [16:32)=Wb[0:16), [32:48)=Wd[16:32), [48:64)=Wb) so
// each wave (64 rows x 32 vcols) holds z1 (nn=0) and z2 (nn=1) of the SAME
// 16 real cols. 8 waves = 4 chunk-rows x 2 col-groups; one wave == one scan
// chunk of 64 t-steps. Epilogue: per-lane 4-run affine products -> 16-step
// shfl exclusive-prefix scan -> chunk totals to LDS -> h_state (32 f32 in
// LDS) carried across m-tiles -> apply + tanh + single write of out.
// T2 XOR swizzle via pre-swizzled global source (rule 21); zero-VALU ds_read
// addressing (swizzle chunk = hi^(fr&7), fragment-independent).
__global__ __launch_bounds__(512, 2) void k_mega(
    const unsigned short* __restrict__ Xb,    // [M][K] bf16 bits
    const unsigned short* __restrict__ Wdb,   // [H][K] bf16 bits
    const unsigned short* __restrict__ Wbb,   // [H][K] bf16 bits
    const float* __restrict__ bd,
    const float* __restrict__ bb,
    const float* __restrict__ A_log,
    const float* __restrict__ h0,             // [B][H]
    float* __restrict__ out)                  // [B][T][H]
{
  __shared__ unsigned short As[2][256 * BK];   // 64 KiB
  __shared__ unsigned short Bs[2][64 * BK];    // 16 KiB
  __shared__ float totA[4][32], totB[4][32];   // chunk affine totals
  __shared__ float h_state[32];                // scan state per col

  const int tid   = threadIdx.x;
  const int wg    = blockIdx.x;
  const int batch = wg & 7;        // == XCD (round-robin dispatch): all 32
  const int jn    = wg >> 3;       //    col-blocks of a batch share one L2
  const int bn    = jn * 32;

  const int w    = tid >> 6;
  const int lane = tid & 63;
  const int c    = w >> 1;         // chunk row-group (64 rows)
  const int g    = w & 1;          // col group (16 real cols)
  const int fr   = lane & 15;
  const int hi   = lane >> 4;
  const int lcol = g * 16 + fr;
  const int gcol = bn + lcol;

  // per-thread column scalars (hoisted out of everything)
  const float bdv = bd[gcol];
  const float bbv = bb[gcol];
  const float Ah  = __expf(A_log[gcol]);

  // ---- staging invariants: pre-swizzled global sources (cg = c^(row&7)) --
  const unsigned short* gA[4];
  int ldsA[4];
#pragma unroll
  for (int jj = 0; jj < 4; jj++) {
    int idx = jj * 512 + tid;      // 0..2047, row 0..255
    int row = idx >> 3;
    int cg  = (idx & 7) ^ (row & 7);
    ldsA[jj] = idx * 16;
    gA[jj] = Xb + (((size_t)(batch * T_DIM + row)) << 10) + (size_t)(cg * 8);
  }
  const unsigned short* gB;
  int ldsB;
  {
    int idx = tid;                 // 512 chunks, vrow 0..63
    int vr  = idx >> 3;
    int cg  = (idx & 7) ^ (vr & 7);
    ldsB = idx * 16;
    int h = bn + (vr >> 5) * 16 + (vr & 15);
    const unsigned short* Wsrc = (vr & 16) ? Wbb : Wdb;
    gB = Wsrc + (((size_t)h) << 10) + (size_t)(cg * 8);
  }

  // ---- ds_read bases: swizzled chunk hi^(fr&7) is fragment-independent ---
  const int ch0 = hi ^ (fr & 7);
  const char* bA0 = (const char*)As + ((c * 64 + fr) * 128 + ch0 * 16);
  const char* bA1 = (const char*)As + ((c * 64 + fr) * 128 + (ch0 ^ 4) * 16);
  const char* bB0 = (const char*)Bs + ((g * 32 + fr) * 128 + ch0 * 16);
  const char* bB1 = (const char*)Bs + ((g * 32 + fr) * 128 + (ch0 ^ 4) * 16);

// tile tt = mt*16 + kt; A elem-offset = mt*256*1024 + kt*64
#define STAGE(TT, D)                                                          \
  do {                                                                        \
    int aOff = (((TT) >> 4) << 18) + (((TT) & 15) << 6);                      \
    int bOff = ((TT) & 15) << 6;                                              \
    _Pragma("unroll")                                                         \
    for (int jj = 0; jj < 4; jj++)                                            \
      gload_lds16(gA[jj] + aOff, (char*)As[D] + ldsA[jj]);                    \
    gload_lds16(gB + bOff, (char*)Bs[D] + ldsB);                              \
  } while (0)

#define TILE(TT, D)                                                           \
  do {                                                                        \
    if ((TT) < NTT - 1) STAGE((TT) + 1, (D) ^ 1);                             \
    bf16x8 Af[8], Bf[4];                                                      \
    _Pragma("unroll")                                                         \
    for (int mm = 0; mm < 4; mm++) {                                          \
      Af[mm * 2 + 0] = *(const bf16x8*)(bA0 + (D) * 32768 + mm * 2048);       \
      Af[mm * 2 + 1] = *(const bf16x8*)(bA1 + (D) * 32768 + mm * 2048);       \
    }                                                                         \
    _Pragma("unroll")                                                         \
    for (int nn = 0; nn < 2; nn++) {                                          \
      Bf[nn * 2 + 0] = *(const bf16x8*)(bB0 + (D) * 8192 + nn * 2048);        \
      Bf[nn * 2 + 1] = *(const bf16x8*)(bB1 + (D) * 8192 + nn * 2048);        \
    }                                                                         \
    __builtin_amdgcn_s_setprio(1);                                            \
    _Pragma("unroll")                                                         \
    for (int mm = 0; mm < 4; mm++)                                            \
      _Pragma("unroll")                                                       \
      for (int nn = 0; nn < 2; nn++)                                          \
        _Pragma("unroll")                                                     \
        for (int kk = 0; kk < 2; kk++)                                        \
          acc[mm][nn] = __builtin_amdgcn_mfma_f32_16x16x32_bf16(              \
              Af[mm * 2 + kk], Bf[nn * 2 + kk], acc[mm][nn], 0, 0, 0);        \
    __builtin_amdgcn_s_setprio(0);                                            \
    asm volatile("s_waitcnt vmcnt(0)" ::: "memory");                          \
    __builtin_amdgcn_s_barrier();                                             \
  } while (0)

  // prologue: stage tile 0, init scan state from h0
  STAGE(0, 0);
  if (tid < 32) h_state[tid] = h0[(batch << 10) + bn + tid];
  asm volatile("s_waitcnt vmcnt(0)" ::: "memory");
  __syncthreads();

  const f32x4 z4 = {0.f, 0.f, 0.f, 0.f};

#pragma unroll 1
  for (int mt = 0; mt < 16; mt++) {
    f32x4 acc[4][2];
#pragma unroll
    for (int m = 0; m < 4; m++) { acc[m][0] = z4; acc[m][1] = z4; }

#pragma unroll 1
    for (int kp = 0; kp < 8; kp++) {
      int tt = mt * 16 + kp * 2;
      TILE(tt, 0);
      TILE(tt + 1, 1);
    }

    // ---- epilogue: nonlinearity + within-chunk prefix scan + apply -------
    // C/D layout: col = lane&15, row-in-frag = hi*4 + r  [m89-verified].
    // t within chunk = m*16 + hi*4 + r; run = 4 consecutive t per (m,hi).
    float rA[4], rB[4], wAp[4][4], wBp[4][4];
#pragma unroll
    for (int m = 0; m < 4; m++) {
      float A_ = 1.f, B_ = 0.f;
#pragma unroll
      for (int r = 0; r < 4; r++) {
        float z1  = acc[m][0][r] + bdv;
        float z2  = acc[m][1][r] + bbv;
        float dlt = softplus_fast(z1);
        float av  = __expf(-dlt * Ah);
        float bv  = dlt * z2;
        B_ = fmaf(av, B_, bv);          // compose (A_,B_) then (av,bv)
        A_ *= av;
        wAp[m][r] = A_; wBp[m][r] = B_; // inclusive within-run prefix
      }
      rA[m] = A_; rB[m] = B_;           // run total
    }
    // exclusive prefix over the 16 runs (t-order rho = m*4 + hi), snapshotted
    float cA = 1.f, cB = 0.f, eA[4], eB[4];
#pragma unroll
    for (int rho = 0; rho < 16; rho++) {
      if ((rho & 3) == hi) { eA[rho >> 2] = cA; eB[rho >> 2] = cB; }
      float sa = __shfl(rA[rho >> 2], (rho & 3) * 16 + fr, 64);
      float sb = __shfl(rB[rho >> 2], (rho & 3) * 16 + fr, 64);
      cB = fmaf(sa, cB, sb);
      cA *= sa;
    }
    // (cA,cB) = full chunk total
    if (hi == 0) { totA[c][lcol] = cA; totB[c][lcol] = cB; }
    __syncthreads();
    float hs = h_state[lcol];           // state before this m-tile
#pragma unroll
    for (int cc = 0; cc < 3; cc++) {    // compose chunks before mine
      float t2 = fmaf(totA[cc][lcol], hs, totB[cc][lcol]);
      hs = (cc < c) ? t2 : hs;
    }
    __syncthreads();                    // all reads of h_state done
    if (c == 3 && hi == 0) h_state[lcol] = fmaf(cA, hs, cB);

    // apply: h_t = (excl ∘ within-run) applied to hs; write tanh(h_t)
    size_t obase = (((size_t)(batch * T_DIM + mt * 256 + c * 64 + hi * 4)) << 10)
                   + (size_t)gcol;
#pragma unroll
    for (int m = 0; m < 4; m++) {
#pragma unroll
      for (int r = 0; r < 4; r++) {
        float aT = eA[m] * wAp[m][r];
        float bT = fmaf(wAp[m][r], eB[m], wBp[m][r]);
        float h  = fmaf(aT, hs, bT);
        out[obase + ((size_t)(m * 16 + r) << 10)] = tanh_fast(h);
      }
    }
  }
#undef TILE
#undef STAGE
}

// ---------- launch ----------
extern "C" void kernel_launch(void* const* d_in, const int* in_sizes, int n_in,
                              void* d_out, int out_size, void* d_ws, size_t ws_size,
                              hipStream_t stream) {
  const float* x     = (const float*)d_in[0];
  const float* h0    = (const float*)d_in[1];
  const float* Wd    = (const float*)d_in[2];
  const float* bd    = (const float*)d_in[3];
  const float* Wb    = (const float*)d_in[4];
  const float* bb    = (const float*)d_in[5];
  const float* A_log = (const float*)d_in[6];
  float* out = (float*)d_out;

  char* ws = (char*)d_ws;
  unsigned short* xb  = (unsigned short*)(ws + 0);           // 64 MiB
  unsigned short* wdb = (unsigned short*)(ws + 67108864);    //  2 MiB
  unsigned short* wbb = (unsigned short*)(ws + 69206016);    //  2 MiB

  // converts
  k_cvt<<<(M_DIM * K_DIM / 8) / 256, 256, 0, stream>>>(x, xb, M_DIM * K_DIM / 8);
  k_cvt<<<(H_DIM * K_DIM / 8) / 256, 256, 0, stream>>>(Wd, wdb, H_DIM * K_DIM / 8);
  k_cvt<<<(H_DIM * K_DIM / 8) / 256, 256, 0, stream>>>(Wb, wbb, H_DIM * K_DIM / 8);

  // fused dual GEMM + chunked scan + tanh, one block per (batch, 32-col)
  k_mega<<<256, 512, 0, stream>>>(xb, wdb, wbb, bd, bb, A_log, h0, out);
}

// Round 9
// 304.612 us; speedup vs baseline: 1.1034x; 1.0389x over previous
//
#include <hip/hip_runtime.h>
#include <math.h>

// Problem constants
#define B_DIM 8
#define T_DIM 4096
#define K_DIM 1024   // IN_DIM
#define H_DIM 1024   // HIDDEN
#define M_DIM (B_DIM * T_DIM)   // 32768 rows
#define BK 64
#define NTT 256             // 16 m-tiles x 16 k-tiles per block

typedef short bf16x8 __attribute__((ext_vector_type(8)));   // 8 bf16 = 4 VGPRs
typedef float f32x4  __attribute__((ext_vector_type(4)));

// ---------- helpers ----------
__device__ __forceinline__ unsigned short f2bf(float f) {
  unsigned int u = __builtin_bit_cast(unsigned int, f);
  u += 0x7FFFu + ((u >> 16) & 1u);   // round-to-nearest-even
  return (unsigned short)(u >> 16);
}

__device__ __forceinline__ void gload_lds16(const void* g, void* l) {
  __builtin_amdgcn_global_load_lds(
      (const __attribute__((address_space(1))) unsigned int*)g,
      (__attribute__((address_space(3))) unsigned int*)l,
      16 /*bytes, literal*/, 0 /*offset*/, 0 /*aux*/);
}

__device__ __forceinline__ float softplus_fast(float x) {
  float e = __expf(-fabsf(x));
  return fmaxf(x, 0.f) + __logf(1.f + e);
}

// fast tanh: 1 - 2/(e^{2x}+1). e=inf -> 1, e=0 -> -1 (correct saturation).
__device__ __forceinline__ float tanh_fast(float x) {
  float e = __expf(2.f * x);
  return 1.f - 2.f * __builtin_amdgcn_rcpf(e + 1.f);
}

// ---------- f32 -> bf16 convert (8 elems/thread) ----------
__global__ __launch_bounds__(256) void k_cvt(const float* __restrict__ in,
                                             unsigned short* __restrict__ out,
                                             int n8) {
  int i = blockIdx.x * 256 + threadIdx.x;
  if (i >= n8) return;
  float4 v0 = ((const float4*)in)[i * 2 + 0];
  float4 v1 = ((const float4*)in)[i * 2 + 1];
  bf16x8 r;
  r[0] = (short)f2bf(v0.x); r[1] = (short)f2bf(v0.y);
  r[2] = (short)f2bf(v0.z); r[3] = (short)f2bf(v0.w);
  r[4] = (short)f2bf(v1.x); r[5] = (short)f2bf(v1.y);
  r[6] = (short)f2bf(v1.z); r[7] = (short)f2bf(v1.w);
  ((bf16x8*)out)[i] = r;
}

// ---------- megakernel v2: dual GEMM + online chunked scan + tanh ----------
// Grid = 8 batches x 64 col-tiles(16 cols) = 512 blocks x 256 thr (4 waves)
// -> 2 blocks/CU (LDS 74.3 KB). Co-resident pair (wg, wg+256) = same batch:
// independent barrier domains (cross-block latency hiding, R2's win) AND
// they stage the same A-tiles -> L2/L1 hits, less X re-fetch drift.
// Each block owns a (batch, 16-col) T-chain: 16 m-tiles of 256 rows.
// Virtual B (32 vrows): vrow[0:16)=Wd cols, [16:32)=Wb cols, so each wave's
// acc[m][0]=z1, acc[m][1]=z2 for the SAME 16 real cols. 4 waves = 4 chunks
// of 64 t-steps. Epilogue per m-tile: per-lane 4-run affine products ->
// 16-step shfl exclusive-prefix scan -> chunk totals via LDS -> h_state
// (16 f32 LDS) carried across m-tiles -> apply + tanh + single out write.
// T2 XOR swizzle via pre-swizzled global source; zero-VALU ds_read bases.
__global__ __launch_bounds__(256, 2) void k_mega(
    const unsigned short* __restrict__ Xb,    // [M][K] bf16 bits
    const unsigned short* __restrict__ Wdb,   // [H][K] bf16 bits
    const unsigned short* __restrict__ Wbb,   // [H][K] bf16 bits
    const float* __restrict__ bd,
    const float* __restrict__ bb,
    const float* __restrict__ A_log,
    const float* __restrict__ h0,             // [B][H]
    float* __restrict__ out)                  // [B][T][H]
{
  __shared__ unsigned short As[2][256 * BK];   // 64 KiB
  __shared__ unsigned short Bs[2][32 * BK];    //  8 KiB
  __shared__ float totA[4][16], totB[4][16];   // chunk affine totals
  __shared__ float h_state[16];                // scan state per col

  const int tid   = threadIdx.x;
  const int wg    = blockIdx.x;
  const int batch = wg & 7;        // == XCD (round-robin dispatch)
  const int jn    = wg >> 3;       // 0..63 col-tile
  const int bn    = jn * 16;

  const int w    = tid >> 6;       // wave = chunk row-group c (0..3)
  const int lane = tid & 63;
  const int c    = w;
  const int fr   = lane & 15;      // column within 16
  const int hi   = lane >> 4;      // row quad
  const int gcol = bn + fr;

  // per-thread column scalars
  const float bdv = bd[gcol];
  const float bbv = bb[gcol];
  const float Ah  = __expf(A_log[gcol]);

  // ---- staging invariants: pre-swizzled global sources (cg = c^(row&7)) --
  const unsigned short* gA[8];
  int ldsA[8];
#pragma unroll
  for (int jj = 0; jj < 8; jj++) {
    int idx = jj * 256 + tid;      // 0..2047, row 0..255
    int row = idx >> 3;
    int cg  = (idx & 7) ^ (row & 7);
    ldsA[jj] = idx * 16;
    gA[jj] = Xb + (((size_t)(batch * T_DIM + row)) << 10) + (size_t)(cg * 8);
  }
  const unsigned short* gB;
  int ldsB;
  {
    int idx = tid;                 // 256 chunks, vrow 0..31
    int vr  = idx >> 3;
    int cg  = (idx & 7) ^ (vr & 7);
    ldsB = idx * 16;
    int h = bn + (vr & 15);
    const unsigned short* Wsrc = (vr & 16) ? Wbb : Wdb;
    gB = Wsrc + (((size_t)h) << 10) + (size_t)(cg * 8);
  }

  // ---- ds_read bases: swizzled chunk hi^(fr&7) is fragment-independent ---
  const int ch0 = hi ^ (fr & 7);
  const char* bA0 = (const char*)As + ((c * 64 + fr) * 128 + ch0 * 16);
  const char* bA1 = (const char*)As + ((c * 64 + fr) * 128 + (ch0 ^ 4) * 16);
  const char* bB0 = (const char*)Bs + (fr * 128 + ch0 * 16);
  const char* bB1 = (const char*)Bs + (fr * 128 + (ch0 ^ 4) * 16);

// tile tt = mt*16 + kt; A elem-offset = mt*256*1024 + kt*64
#define STAGE(TT, D)                                                          \
  do {                                                                        \
    int aOff = (((TT) >> 4) << 18) + (((TT) & 15) << 6);                      \
    int bOff = ((TT) & 15) << 6;                                              \
    _Pragma("unroll")                                                         \
    for (int jj = 0; jj < 8; jj++)                                            \
      gload_lds16(gA[jj] + aOff, (char*)As[D] + ldsA[jj]);                    \
    gload_lds16(gB + bOff, (char*)Bs[D] + ldsB);                              \
  } while (0)

#define TILE(TT, D)                                                           \
  do {                                                                        \
    if ((TT) < NTT - 1) STAGE((TT) + 1, (D) ^ 1);                             \
    bf16x8 Af[8], Bf[4];                                                      \
    _Pragma("unroll")                                                         \
    for (int mm = 0; mm < 4; mm++) {                                          \
      Af[mm * 2 + 0] = *(const bf16x8*)(bA0 + (D) * 32768 + mm * 2048);       \
      Af[mm * 2 + 1] = *(const bf16x8*)(bA1 + (D) * 32768 + mm * 2048);       \
    }                                                                         \
    _Pragma("unroll")                                                         \
    for (int nn = 0; nn < 2; nn++) {                                          \
      Bf[nn * 2 + 0] = *(const bf16x8*)(bB0 + (D) * 4096 + nn * 2048);        \
      Bf[nn * 2 + 1] = *(const bf16x8*)(bB1 + (D) * 4096 + nn * 2048);        \
    }                                                                         \
    __builtin_amdgcn_s_setprio(1);                                            \
    _Pragma("unroll")                                                         \
    for (int mm = 0; mm < 4; mm++)                                            \
      _Pragma("unroll")                                                       \
      for (int nn = 0; nn < 2; nn++)                                          \
        _Pragma("unroll")                                                     \
        for (int kk = 0; kk < 2; kk++)                                        \
          acc[mm][nn] = __builtin_amdgcn_mfma_f32_16x16x32_bf16(              \
              Af[mm * 2 + kk], Bf[nn * 2 + kk], acc[mm][nn], 0, 0, 0);        \
    __builtin_amdgcn_s_setprio(0);                                            \
    asm volatile("s_waitcnt vmcnt(0)" ::: "memory");                          \
    __builtin_amdgcn_s_barrier();                                             \
  } while (0)

  // prologue: stage tile 0, init scan state from h0
  STAGE(0, 0);
  if (tid < 16) h_state[tid] = h0[(batch << 10) + bn + tid];
  asm volatile("s_waitcnt vmcnt(0)" ::: "memory");
  __syncthreads();

  const f32x4 z4 = {0.f, 0.f, 0.f, 0.f};

#pragma unroll 1
  for (int mt = 0; mt < 16; mt++) {
    f32x4 acc[4][2];
#pragma unroll
    for (int m = 0; m < 4; m++) { acc[m][0] = z4; acc[m][1] = z4; }

#pragma unroll 1
    for (int kp = 0; kp < 8; kp++) {
      int tt = mt * 16 + kp * 2;
      TILE(tt, 0);
      TILE(tt + 1, 1);
    }

    // ---- epilogue: nonlinearity + within-chunk prefix scan + apply -------
    // C/D layout: col = lane&15, row-in-frag = hi*4 + r  [m89-verified].
    // t within chunk = m*16 + hi*4 + r; run = 4 consecutive t per (m,hi).
    float rA[4], rB[4], wAp[4][4], wBp[4][4];
#pragma unroll
    for (int m = 0; m < 4; m++) {
      float A_ = 1.f, B_ = 0.f;
#pragma unroll
      for (int r = 0; r < 4; r++) {
        float z1  = acc[m][0][r] + bdv;
        float z2  = acc[m][1][r] + bbv;
        float dlt = softplus_fast(z1);
        float av  = __expf(-dlt * Ah);
        float bv  = dlt * z2;
        B_ = fmaf(av, B_, bv);          // compose (A_,B_) then (av,bv)
        A_ *= av;
        wAp[m][r] = A_; wBp[m][r] = B_; // inclusive within-run prefix
      }
      rA[m] = A_; rB[m] = B_;           // run total
    }
    // exclusive prefix over the 16 runs (t-order rho = m*4 + hi), snapshotted
    float cA = 1.f, cB = 0.f, eA[4], eB[4];
#pragma unroll
    for (int rho = 0; rho < 16; rho++) {
      if ((rho & 3) == hi) { eA[rho >> 2] = cA; eB[rho >> 2] = cB; }
      float sa = __shfl(rA[rho >> 2], (rho & 3) * 16 + fr, 64);
      float sb = __shfl(rB[rho >> 2], (rho & 3) * 16 + fr, 64);
      cB = fmaf(sa, cB, sb);
      cA *= sa;
    }
    // (cA,cB) = full chunk total
    if (hi == 0) { totA[c][fr] = cA; totB[c][fr] = cB; }
    __syncthreads();
    float hs = h_state[fr];             // state before this m-tile
#pragma unroll
    for (int cc = 0; cc < 3; cc++) {    // compose chunks before mine
      float t2 = fmaf(totA[cc][fr], hs, totB[cc][fr]);
      hs = (cc < c) ? t2 : hs;
    }
    __syncthreads();                    // all reads of h_state done
    if (c == 3 && hi == 0) h_state[fr] = fmaf(cA, hs, cB);

    // apply: h_t = (excl ∘ within-run) applied to hs; write tanh(h_t)
    size_t obase = (((size_t)(batch * T_DIM + mt * 256 + c * 64 + hi * 4)) << 10)
                   + (size_t)gcol;
#pragma unroll
    for (int m = 0; m < 4; m++) {
#pragma unroll
      for (int r = 0; r < 4; r++) {
        float aT = eA[m] * wAp[m][r];
        float bT = fmaf(wAp[m][r], eB[m], wBp[m][r]);
        float h  = fmaf(aT, hs, bT);
        out[obase + ((size_t)(m * 16 + r) << 10)] = tanh_fast(h);
      }
    }
  }
#undef TILE
#undef STAGE
}

// ---------- launch ----------
extern "C" void kernel_launch(void* const* d_in, const int* in_sizes, int n_in,
                              void* d_out, int out_size, void* d_ws, size_t ws_size,
                              hipStream_t stream) {
  const float* x     = (const float*)d_in[0];
  const float* h0    = (const float*)d_in[1];
  const float* Wd    = (const float*)d_in[2];
  const float* bd    = (const float*)d_in[3];
  const float* Wb    = (const float*)d_in[4];
  const float* bb    = (const float*)d_in[5];
  const float* A_log = (const float*)d_in[6];
  float* out = (float*)d_out;

  char* ws = (char*)d_ws;
  unsigned short* xb  = (unsigned short*)(ws + 0);           // 64 MiB
  unsigned short* wdb = (unsigned short*)(ws + 67108864);    //  2 MiB
  unsigned short* wbb = (unsigned short*)(ws + 69206016);    //  2 MiB

  // converts
  k_cvt<<<(M_DIM * K_DIM / 8) / 256, 256, 0, stream>>>(x, xb, M_DIM * K_DIM / 8);
  k_cvt<<<(H_DIM * K_DIM / 8) / 256, 256, 0, stream>>>(Wd, wdb, H_DIM * K_DIM / 8);
  k_cvt<<<(H_DIM * K_DIM / 8) / 256, 256, 0, stream>>>(Wb, wbb, H_DIM * K_DIM / 8);

  // fused dual GEMM + chunked scan + tanh; 512 blocks (2/CU), 256 thr
  k_mega<<<512, 256, 0, stream>>>(xb, wdb, wbb, bd, bb, A_log, h0, out);
}